// Round 1
// 151.260 us; speedup vs baseline: 1.0655x; 1.0655x over previous
//
#include <hip/hip_runtime.h>

#define TT 4096          // signal length
#define NN 8192          // padded length
#define NF 4096          // FFT length = 16^3

// XOR swizzle: permutes low 4 bits by a hash of the row; measured ~2% LDS
// bank-conflict overhead in R4 across all access patterns used here.
#define SW(i) ((i) ^ ((((i) >> 4) ^ ((i) >> 8)) & 15))

// hardware sin/cos of 2*pi*x (x in revolutions); args here are exact dyadics
__device__ __forceinline__ float sin2pi(float x) { return __builtin_amdgcn_sinf(x); }
__device__ __forceinline__ float cos2pi(float x) { return __builtin_amdgcn_cosf(x); }

// (ar,ai) *= (br,bi)
#define WMUL(ar, ai, br, bi) { float _t = (ar)*(br) - (ai)*(bi); \
                               (ai) = (ar)*(bi) + (ai)*(br); (ar) = _t; }

// e^{i*2*pi/32} — step for k -> k+256 at N=8192
#define C32 0.9807852804032304f
#define S32 0.19509032201612825f

// -------------------- register DFT16 (two radix-4 layers, DIT) --------------
// S = -1: forward (e^{-i}), S = +1: inverse (e^{+i}).
template<int S>
__device__ __forceinline__ void dft4(float& ar, float& ai, float& br, float& bi,
                                     float& cr, float& ci, float& er, float& ei) {
    float t0r = ar + cr, t0i = ai + ci;
    float t1r = ar - cr, t1i = ai - ci;
    float t2r = br + er, t2i = bi + ei;
    float t3r = br - er, t3i = bi - ei;
    ar = t0r + t2r; ai = t0i + t2i;
    cr = t0r - t2r; ci = t0i - t2i;
    br = t1r - S * t3i; bi = t1i + S * t3r;
    er = t1r + S * t3i; ei = t1i - S * t3r;
}

#define DFT16_TMULS(S, xr, xi) { \
    const float C1 = 0.9238795325112867f; \
    const float S1 = 0.3826834323650898f; \
    const float R2 = 0.7071067811865476f; \
    { float _r = xr[5]*(C1) - xi[5]*(S*S1);  xi[5]  = xr[5]*(S*S1)  + xi[5]*(C1);  xr[5]  = _r; } \
    { float _r = xr[9]*(R2) - xi[9]*(S*R2);  xi[9]  = xr[9]*(S*R2)  + xi[9]*(R2);  xr[9]  = _r; } \
    { float _r = xr[13]*(S1) - xi[13]*(S*C1); xi[13] = xr[13]*(S*C1) + xi[13]*(S1); xr[13] = _r; } \
    { float _r = xr[6]*(R2) - xi[6]*(S*R2);  xi[6]  = xr[6]*(S*R2)  + xi[6]*(R2);  xr[6]  = _r; } \
    { float _r = -S * xi[10]; xi[10] = S * xr[10]; xr[10] = _r; } \
    { float _r = xr[14]*(-R2) - xi[14]*(S*R2); xi[14] = xr[14]*(S*R2) + xi[14]*(-R2); xr[14] = _r; } \
    { float _r = xr[7]*(S1) - xi[7]*(S*C1);  xi[7]  = xr[7]*(S*C1)  + xi[7]*(S1);  xr[7]  = _r; } \
    { float _r = xr[11]*(-R2) - xi[11]*(S*R2); xi[11] = xr[11]*(S*R2) + xi[11]*(-R2); xr[11] = _r; } \
    { float _r = xr[15]*(-C1) - xi[15]*(-S*S1); xi[15] = xr[15]*(-S*S1) + xi[15]*(-C1); xr[15] = _r; } }

template<int S>
__device__ __forceinline__ void dft16(float xr[16], float xi[16]) {
    #pragma unroll
    for (int n0 = 0; n0 < 4; ++n0)
        dft4<S>(xr[n0], xi[n0], xr[n0 + 4], xi[n0 + 4],
                xr[n0 + 8], xi[n0 + 8], xr[n0 + 12], xi[n0 + 12]);

    DFT16_TMULS(S, xr, xi)

    #pragma unroll
    for (int k0 = 0; k0 < 4; ++k0)
        dft4<S>(xr[4*k0], xi[4*k0], xr[4*k0+1], xi[4*k0+1],
                xr[4*k0+2], xi[4*k0+2], xr[4*k0+3], xi[4*k0+3]);

    float tr[16], ti[16];
    #pragma unroll
    for (int q = 0; q < 16; ++q) { int p = 4*(q & 3) + (q >> 2); tr[q] = xr[p]; ti[q] = xi[p]; }
    #pragma unroll
    for (int q = 0; q < 16; ++q) { xr[q] = tr[q]; xi[q] = ti[q]; }
}

// Pruned final-stage DFT16: only natural outputs q in [4,12) are ever read by
// the epilogue (tp in [1024,3072)).  Output transpose p = 4*(q&3)+(q>>2) means
// we need only the "b" (p%4==1 -> q=4+k0) and "c" (p%4==2 -> q=8+k0) outputs
// of each second-layer dft4.  yr/yi[k0] = q=4+k0, yr/yi[4+k0] = q=8+k0.
template<int S>
__device__ __forceinline__ void dft16_mid8(float xr[16], float xi[16],
                                           float yr[8], float yi[8]) {
    #pragma unroll
    for (int n0 = 0; n0 < 4; ++n0)
        dft4<S>(xr[n0], xi[n0], xr[n0 + 4], xi[n0 + 4],
                xr[n0 + 8], xi[n0 + 8], xr[n0 + 12], xi[n0 + 12]);

    DFT16_TMULS(S, xr, xi)

    #pragma unroll
    for (int k0 = 0; k0 < 4; ++k0) {
        float ar = xr[4*k0],     ai = xi[4*k0];
        float br = xr[4*k0 + 1], bi = xi[4*k0 + 1];
        float cr = xr[4*k0 + 2], ci = xi[4*k0 + 2];
        float er = xr[4*k0 + 3], ei = xi[4*k0 + 3];
        float t0r = ar + cr, t0i = ai + ci;
        float t1r = ar - cr, t1i = ai - ci;
        float t2r = br + er, t2i = bi + ei;
        float t3r = br - er, t3i = bi - ei;
        yr[k0]     = t1r - S * t3i;  yi[k0]     = t1i + S * t3r;  // natural q = 4+k0
        yr[4 + k0] = t0r - t2r;      yi[4 + k0] = t0i - t2i;      // natural q = 8+k0
    }
}

__device__ __forceinline__ int refl(int p) {
    if (p < 2048) return 2047 - p;
    if (p < 6144) return p - 2048;
    return 10239 - p;
}

// -------------------- forward: real-8192 FFT via packed complex-4096 ---------
// Staging is fused into stage-0 registers (the old staging wrote exactly the
// per-thread set stage 0 re-read; no barrier separated them).  All twiddle
// sincos chains replaced by complex-mul recurrences with an exact midpoint
// reset (w^8 via fresh sincos of a dyadic angle, or e^{i*pi/2} rotation).
__global__ __launch_bounds__(256) void fwd_kernel(const float* __restrict__ in,
                                                  float2* __restrict__ F) {
    __shared__ float2 lds[NF];
    const int b = blockIdx.x, tid = threadIdx.x;
    const float* row = in + b * TT;

    float xr[16], xi[16];

    // ---- staging + stage 0 (stride 256), fused in registers ----
    #pragma unroll
    for (int r = 0; r < 16; ++r) {
        const int i = tid + 256 * r;
        xr[r] = row[refl(2 * i)];
        xi[r] = row[refl(2 * i + 1)];
    }
    dft16<-1>(xr, xi);
    {
        const float w1r = cos2pi((float)tid * (1.0f / 4096.0f));
        const float w1i = -sin2pi((float)tid * (1.0f / 4096.0f));
        const float w8r = cos2pi((float)tid * (1.0f / 512.0f));
        const float w8i = -sin2pi((float)tid * (1.0f / 512.0f));
        float wr = w1r, wi = w1i;
        #pragma unroll
        for (int q = 1; q < 16; ++q) {
            float _r = xr[q]*wr - xi[q]*wi;
            xi[q] = xr[q]*wi + xi[q]*wr; xr[q] = _r;
            if (q == 7) { wr = w8r; wi = w8i; }       // exact reset: w^8
            else        { WMUL(wr, wi, w1r, w1i) }
        }
    }
    #pragma unroll
    for (int q = 0; q < 16; ++q) lds[SW(tid + 256 * q)] = make_float2(xr[q], xi[q]);
    __syncthreads();

    // ---- stage 1 (stride 16) ----
    {
        const int j = tid & 15;
        const int base = ((tid >> 4) << 8) + j;
        #pragma unroll
        for (int q = 0; q < 16; ++q) {
            float2 v = lds[SW(base + 16 * q)];
            xr[q] = v.x; xi[q] = v.y;
        }
        dft16<-1>(xr, xi);
        const float w1r = cos2pi((float)j * (1.0f / 256.0f));
        const float w1i = -sin2pi((float)j * (1.0f / 256.0f));
        const float w8r = cos2pi((float)j * (1.0f / 32.0f));
        const float w8i = -sin2pi((float)j * (1.0f / 32.0f));
        float wr = w1r, wi = w1i;
        #pragma unroll
        for (int q = 1; q < 16; ++q) {
            float _r = xr[q]*wr - xi[q]*wi;
            xi[q] = xr[q]*wi + xi[q]*wr; xr[q] = _r;
            if (q == 7) { wr = w8r; wi = w8i; }
            else        { WMUL(wr, wi, w1r, w1i) }
        }
        #pragma unroll
        for (int q = 0; q < 16; ++q) lds[SW(base + 16 * q)] = make_float2(xr[q], xi[q]);
    }
    __syncthreads();

    // ---- stage 2 (twiddle-free) + natural-order scatter ----
    {
        const int base = tid << 4;
        const int f2 = (tid ^ (tid >> 4)) & 15;
        #pragma unroll
        for (int q = 0; q < 16; ++q) {
            float2 v = lds[base + (q ^ f2)];
            xr[q] = v.x; xi[q] = v.y;
        }
        dft16<-1>(xr, xi);
        __syncthreads();
        const int c = tid & 15;
        const int h = tid >> 4;
        #pragma unroll
        for (int q = 0; q < 16; ++q)
            lds[(q << 8) + (c << 4) + (h ^ c ^ q)] = make_float2(xr[q], xi[q]);
    }
    __syncthreads();

    // ---- epilogue: unpack real FFT; twiddle (c,s) by recurrence over r ----
    {
        const float c0 = cos2pi((float)(tid + 1) * (1.0f / 8192.0f));
        const float s0 = sin2pi((float)(tid + 1) * (1.0f / 8192.0f));
        float cc = c0, ss = s0;
        #pragma unroll
        for (int r = 0; r < 16; ++r) {
            const int i = tid + 256 * r;
            const int k = i + 1;
            const float2 za = lds[SW(k & (NF - 1))];
            const float2 zb = lds[SW((NF - k) & (NF - 1))];
            const float fer = 0.5f * (za.x + zb.x), fei = 0.5f * (za.y - zb.y);
            const float fo_r = 0.5f * (za.y + zb.y), fo_i = -0.5f * (za.x - zb.x);
            F[b * NF + i] = make_float2(fer + cc * fo_r + ss * fo_i,
                                        fei + cc * fo_i - ss * fo_r);
            if (r == 7) { cc = -s0; ss = c0; }        // exact: * e^{i*pi/2}
            else        { WMUL(cc, ss, C32, S32) }
        }
    }
}

// -------------------- inverse: one block per (batch, scale) ------------------
// d_k = F[b,k]*wft[j,k+1]; half-band 8192-IFFT = two 4096-IFFTs computed
// TOGETHER as one 2-vector FFT (signal0 = even samples, signal1 = odd).
// Changes vs prior version: staging fused into stage-0 registers (no initial
// LDS round-trip), twiddle recurrences instead of per-q sincos, and the final
// stage computes/scatters only the 8 of 16 outputs the epilogue reads.
__global__ __launch_bounds__(256) void inv_kernel(const float2* __restrict__ F,
                                                  const float* __restrict__ wft,
                                                  float* __restrict__ out,
                                                  int NS) {
    __shared__ float4 lds[NF];                 // 64 KB -> 2 blocks/CU
    const int blk = blockIdx.x;
    const int b = blk / NS;
    const int j = blk - b * NS;
    const int tid = threadIdx.x;

    const float2* Frow = F + b * NF;
    const float* wrow = wft + (size_t)j * NN + 1;
    float* orow = out + (size_t)(b * NS + j) * TT;
    const float LOGN = 9.0109131020007136f;       // log(8192)
    const float HALF_LN2 = 0.34657359027997264f;  // 0.5 * ln(2)

    float xr0[16], xi0[16], xr1[16], xi1[16];

    #define CMUL2(q, wr, wi) { \
        float _r0 = xr0[q]*(wr) - xi0[q]*(wi); xi0[q] = xr0[q]*(wi) + xi0[q]*(wr); xr0[q] = _r0; \
        float _r1 = xr1[q]*(wr) - xi1[q]*(wi); xi1[q] = xr1[q]*(wi) + xi1[q]*(wr); xr1[q] = _r1; }

    // ---- staging + stage 0 (stride 256), fused in registers ----
    // d0 = F*w ; d1 = d0 * e^{+2*pi*i*k/8192}, k = tid + 256*r.
    // Twiddle advances by exact e^{i*2pi/32} per r; exact e^{i*pi/2} reset at r=8.
    {
        const float c0 = cos2pi((float)tid * (1.0f / 8192.0f));
        const float s0 = sin2pi((float)tid * (1.0f / 8192.0f));
        float cr = c0, ci = s0;
        #pragma unroll
        for (int r = 0; r < 16; ++r) {
            const int k = tid + 256 * r;
            const float2 f = Frow[k];
            const float w = wrow[k];
            const float d0r = f.x * w, d0i = f.y * w;
            xr0[r] = d0r; xi0[r] = d0i;
            xr1[r] = d0r * cr - d0i * ci;
            xi1[r] = d0r * ci + d0i * cr;
            if (r == 7) { cr = -s0; ci = c0; }
            else        { WMUL(cr, ci, C32, S32) }
        }
    }
    dft16<1>(xr0, xi0);
    dft16<1>(xr1, xi1);
    {
        const float w1r = cos2pi((float)tid * (1.0f / 4096.0f));
        const float w1i = sin2pi((float)tid * (1.0f / 4096.0f));
        const float w8r = cos2pi((float)tid * (1.0f / 512.0f));
        const float w8i = sin2pi((float)tid * (1.0f / 512.0f));
        float wr = w1r, wi = w1i;
        #pragma unroll
        for (int q = 1; q < 16; ++q) {
            CMUL2(q, wr, wi)
            if (q == 7) { wr = w8r; wi = w8i; }
            else        { WMUL(wr, wi, w1r, w1i) }
        }
    }
    #pragma unroll
    for (int q = 0; q < 16; ++q)
        lds[SW(tid + 256 * q)] = make_float4(xr0[q], xi0[q], xr1[q], xi1[q]);
    __syncthreads();

    // ---- stage 1: stride 16, j = tid&15 ----
    {
        const int jj = tid & 15;
        const int base = ((tid >> 4) << 8) + jj;
        #pragma unroll
        for (int q = 0; q < 16; ++q) {
            float4 v = lds[SW(base + 16 * q)];
            xr0[q] = v.x; xi0[q] = v.y; xr1[q] = v.z; xi1[q] = v.w;
        }
        dft16<1>(xr0, xi0);
        dft16<1>(xr1, xi1);
        const float w1r = cos2pi((float)jj * (1.0f / 256.0f));
        const float w1i = sin2pi((float)jj * (1.0f / 256.0f));
        const float w8r = cos2pi((float)jj * (1.0f / 32.0f));
        const float w8i = sin2pi((float)jj * (1.0f / 32.0f));
        float wr = w1r, wi = w1i;
        #pragma unroll
        for (int q = 1; q < 16; ++q) {
            CMUL2(q, wr, wi)
            if (q == 7) { wr = w8r; wi = w8i; }
            else        { WMUL(wr, wi, w1r, w1i) }
        }
        #pragma unroll
        for (int q = 0; q < 16; ++q)
            lds[SW(base + 16 * q)] = make_float4(xr0[q], xi0[q], xr1[q], xi1[q]);
    }
    __syncthreads();

    // ---- stage 2: contiguous 16/thread, twiddle-free; pruned to the 8
    //      natural outputs q in [4,12) the epilogue reads; scatter natural ----
    {
        const int base = tid << 4;
        const int f2 = (tid ^ (tid >> 4)) & 15;
        #pragma unroll
        for (int q = 0; q < 16; ++q) {
            float4 v = lds[base + (q ^ f2)];
            xr0[q] = v.x; xi0[q] = v.y; xr1[q] = v.z; xi1[q] = v.w;
        }
        float yr0[8], yi0[8], yr1[8], yi1[8];
        dft16_mid8<1>(xr0, xi0, yr0, yi0);
        dft16_mid8<1>(xr1, xi1, yr1, yi1);
        __syncthreads();
        const int c = tid & 15;
        const int h = tid >> 4;
        #pragma unroll
        for (int k0 = 0; k0 < 4; ++k0) {
            const int qa = 4 + k0;
            const int qb = 8 + k0;
            lds[(qa << 8) + (c << 4) + (h ^ c ^ qa)] =
                make_float4(yr0[k0], yi0[k0], yr1[k0], yi1[k0]);
            lds[(qb << 8) + (c << 4) + (h ^ c ^ qb)] =
                make_float4(yr0[4 + k0], yi0[4 + k0], yr1[4 + k0], yi1[4 + k0]);
        }
    }
    __syncthreads();

    #pragma unroll
    for (int i2 = 0; i2 < 8; ++i2) {
        const int tp = 1024 + tid + 256 * i2;   // t_global = 2*tp+{0,1} in [2048,6144)
        const float4 z = lds[SW(tp)];
        const float m0 = z.x * z.x + z.y * z.y;
        const float m1 = z.z * z.z + z.w * z.w;
        const float v0 = HALF_LN2 * __builtin_amdgcn_logf(m0) - LOGN;
        const float v1 = HALF_LN2 * __builtin_amdgcn_logf(m1) - LOGN;
        ((float2*)orow)[tid + 256 * i2] = make_float2(v0, v1);
    }
    #undef CMUL2
}

extern "C" void kernel_launch(void* const* d_in, const int* in_sizes, int n_in,
                              void* d_out, int out_size, void* d_ws, size_t ws_size,
                              hipStream_t stream) {
    const float* inputs = (const float*)d_in[0];
    const float* wft = (const float*)d_in[1];
    float* out = (float*)d_out;

    const int B = in_sizes[0] / TT;     // 64
    const int NS = in_sizes[1] / NN;    // 75

    float2* F = (float2*)d_ws;          // B*4096 complex = 2 MB

    hipLaunchKernelGGL(fwd_kernel, dim3(B), dim3(256), 0, stream, inputs, F);
    hipLaunchKernelGGL(inv_kernel, dim3(B * NS), dim3(256), 0, stream, F, wft, out, NS);
}